// Round 1
// baseline (977.767 us; speedup 1.0000x reference)
//
#include <hip/hip_runtime.h>

typedef __attribute__((ext_vector_type(8))) short short8;
typedef __attribute__((ext_vector_type(4))) float f32x4;

#define MFMA_BF16 __builtin_amdgcn_mfma_f32_16x16x32_bf16

__device__ __forceinline__ unsigned short f2bf(float f) {
    unsigned int u = __builtin_bit_cast(unsigned int, f);
    u = (u + 0x7FFFu + ((u >> 16) & 1u)) >> 16;
    return (unsigned short)u;
}

constexpr int D  = 768;
constexpr int S  = 4096;

// ---------------- QKV GEMM: [16384,768] x [768,768] -> bf16 ----------------
// z=0: q row-major, z=1: k row-major, z=2: v transposed vt[b][d][s]
__global__ __launch_bounds__(256)
void qkv_gemm(const float* __restrict__ x,
              const float* __restrict__ Wq, const float* __restrict__ Wk,
              const float* __restrict__ Wv,
              unsigned short* __restrict__ qo, unsigned short* __restrict__ ko,
              unsigned short* __restrict__ vt)
{
    __shared__ unsigned short sA[128][40];   // [m][k] bf16, pad 40 to break conflicts
    __shared__ unsigned short sB[128][40];   // [n][k] bf16 (transposed W chunk)
    const int tid  = threadIdx.x;
    const int lane = tid & 63;
    const int w    = tid >> 6;            // 0..3
    const int wr   = w >> 1, wc = w & 1;  // 2x2 wave grid over 128x128
    const int bm   = blockIdx.x * 128;
    const int bn   = blockIdx.y * 128;
    const int z    = blockIdx.z;
    const float* __restrict__ W = (z == 0) ? Wq : ((z == 1) ? Wk : Wv);

    f32x4 acc[4][4] = {};

    for (int kc = 0; kc < 24; ++kc) {      // K = 768 = 24 * 32
        const int k0 = kc * 32;
        __syncthreads();
        // stage A: 128x32 fp32 -> bf16, coalesced float4 loads
        #pragma unroll
        for (int i = 0; i < 4; ++i) {
            const int e   = (i * 256 + tid) * 4;
            const int row = e >> 5, col = e & 31;
            const float4 v = *reinterpret_cast<const float4*>(x + (size_t)(bm + row) * D + k0 + col);
            unsigned int lo = f2bf(v.x) | ((unsigned int)f2bf(v.y) << 16);
            unsigned int hi = f2bf(v.z) | ((unsigned int)f2bf(v.w) << 16);
            uint2 pk; pk.x = lo; pk.y = hi;
            *reinterpret_cast<uint2*>(&sA[row][col]) = pk;
        }
        // stage B: 32x128 fp32, write transposed [n][k]
        #pragma unroll
        for (int i = 0; i < 4; ++i) {
            const int e  = (i * 256 + tid) * 4;
            const int kr = e >> 7, c = e & 127;
            const float4 v = *reinterpret_cast<const float4*>(W + (size_t)(k0 + kr) * D + bn + c);
            sB[c + 0][kr] = f2bf(v.x);
            sB[c + 1][kr] = f2bf(v.y);
            sB[c + 2][kr] = f2bf(v.z);
            sB[c + 3][kr] = f2bf(v.w);
        }
        __syncthreads();
        short8 af[4], bf[4];
        #pragma unroll
        for (int fr = 0; fr < 4; ++fr)
            af[fr] = *reinterpret_cast<const short8*>(&sA[wr * 64 + fr * 16 + (lane & 15)][(lane >> 4) * 8]);
        #pragma unroll
        for (int fc = 0; fc < 4; ++fc)
            bf[fc] = *reinterpret_cast<const short8*>(&sB[wc * 64 + fc * 16 + (lane & 15)][(lane >> 4) * 8]);
        #pragma unroll
        for (int fr = 0; fr < 4; ++fr)
            #pragma unroll
            for (int fc = 0; fc < 4; ++fc)
                acc[fr][fc] = MFMA_BF16(af[fr], bf[fc], acc[fr][fc], 0, 0, 0);
    }

    #pragma unroll
    for (int fr = 0; fr < 4; ++fr) {
        #pragma unroll
        for (int fc = 0; fc < 4; ++fc) {
            #pragma unroll
            for (int r = 0; r < 4; ++r) {
                const int m = bm + wr * 64 + fr * 16 + (lane >> 4) * 4 + r;  // C: row=(lane>>4)*4+reg
                const int n = bn + wc * 64 + fc * 16 + (lane & 15);          //    col=lane&15
                const unsigned short hv = f2bf(acc[fr][fc][r]);
                if (z == 0)      qo[(size_t)m * D + n] = hv;
                else if (z == 1) ko[(size_t)m * D + n] = hv;
                else {
                    const int bb = m >> 12;           // m = b*4096 + s
                    const int s  = m & (S - 1);
                    vt[((size_t)bb * D + n) * S + s] = hv;
                }
            }
        }
    }
}

// ---------------- Flash attention, causal, D=768 ----------------
// 1 WG = 512 thr (8 waves) handles 64 q-rows of one batch.
// QK^T: wave w -> rows 16*(w>>1), key-cols 32*(w&1); d staged in 64-chunks.
// PV:   wave w -> d-slice w*96..w*96+96, acc fp32 4x6 frags (96 VGPR).
__global__ __launch_bounds__(512)
void attn_fwd(const unsigned short* __restrict__ Qg, const unsigned short* __restrict__ Kg,
              const unsigned short* __restrict__ Vt, float* __restrict__ out)
{
    __shared__ unsigned short sQ[64][72];
    __shared__ unsigned short sK[64][72];
    __shared__ float          sS[64][68];
    __shared__ unsigned short sP[64][72];
    __shared__ float m_run[64], l_run[64], resc[64];

    const int tid   = threadIdx.x;
    const int lane  = tid & 63;
    const int w     = tid >> 6;       // 0..7
    const int qtile = blockIdx.x;
    const int b     = blockIdx.y;
    const float scale = 0.03608439182435161f;  // 1/sqrt(768)

    if (tid < 64) { m_run[tid] = -1e30f; l_run[tid] = 0.0f; }

    f32x4 acc[4][6] = {};

    const size_t qbase = ((size_t)b * S + (size_t)qtile * 64) * D;

    for (int kt = 0; kt <= qtile; ++kt) {
        const size_t kbase = ((size_t)b * S + (size_t)kt * 64) * D;
        f32x4 qk[2] = {};
        const int wr = w >> 1, wc = w & 1;

        // ---- QK^T over d-chunks of 64 ----
        for (int dc = 0; dc < 12; ++dc) {
            __syncthreads();
            {
                const int row = tid >> 3, col = (tid & 7) * 8;
                *reinterpret_cast<short8*>(&sQ[row][col]) =
                    *reinterpret_cast<const short8*>(Qg + qbase + (size_t)row * D + dc * 64 + col);
                *reinterpret_cast<short8*>(&sK[row][col]) =
                    *reinterpret_cast<const short8*>(Kg + kbase + (size_t)row * D + dc * 64 + col);
            }
            __syncthreads();
            #pragma unroll
            for (int ks = 0; ks < 2; ++ks) {
                short8 a = *reinterpret_cast<const short8*>(&sQ[wr * 16 + (lane & 15)][ks * 32 + (lane >> 4) * 8]);
                #pragma unroll
                for (int fc = 0; fc < 2; ++fc) {
                    short8 bv = *reinterpret_cast<const short8*>(&sK[wc * 32 + fc * 16 + (lane & 15)][ks * 32 + (lane >> 4) * 8]);
                    qk[fc] = MFMA_BF16(a, bv, qk[fc], 0, 0, 0);
                }
            }
        }
        // write S tile (fp32, raw scores)
        #pragma unroll
        for (int fc = 0; fc < 2; ++fc)
            #pragma unroll
            for (int r = 0; r < 4; ++r)
                sS[wr * 16 + (lane >> 4) * 4 + r][wc * 32 + fc * 16 + (lane & 15)] = qk[fc][r];
        __syncthreads();

        // ---- online softmax: 8 threads per row, 8 cols each ----
        {
            const int r = tid >> 3, j = tid & 7;
            const int qrow = qtile * 64 + r;
            float tv[8];
            float mx = -1e30f;
            #pragma unroll
            for (int i = 0; i < 8; ++i) {
                const int c = kt * 64 + j * 8 + i;
                const float sv = sS[r][j * 8 + i] * scale;
                tv[i] = (c <= qrow) ? sv : -1e30f;
                mx = fmaxf(mx, tv[i]);
            }
            mx = fmaxf(mx, __shfl_xor(mx, 1));
            mx = fmaxf(mx, __shfl_xor(mx, 2));
            mx = fmaxf(mx, __shfl_xor(mx, 4));
            const float mold = m_run[r];
            const float mnew = fmaxf(mold, mx);
            const float sc   = __expf(mold - mnew);
            float ls = 0.0f;
            #pragma unroll
            for (int i = 0; i < 8; ++i) {
                const float p = __expf(tv[i] - mnew);
                ls += p;
                sP[r][j * 8 + i] = f2bf(p);
            }
            ls += __shfl_xor(ls, 1);
            ls += __shfl_xor(ls, 2);
            ls += __shfl_xor(ls, 4);
            if (j == 0) {
                l_run[r] = l_run[r] * sc + ls;
                m_run[r] = mnew;
                resc[r]  = sc;
            }
        }
        __syncthreads();

        // ---- PV: rescale acc, then P @ V^T-slice ----
        #pragma unroll
        for (int fr = 0; fr < 4; ++fr)
            #pragma unroll
            for (int r = 0; r < 4; ++r) {
                const float scr = resc[fr * 16 + (lane >> 4) * 4 + r];
                #pragma unroll
                for (int fc = 0; fc < 6; ++fc) acc[fr][fc][r] *= scr;
            }
        #pragma unroll
        for (int ks = 0; ks < 2; ++ks) {
            short8 bv[6];
            #pragma unroll
            for (int fc = 0; fc < 6; ++fc) {
                const int d = w * 96 + fc * 16 + (lane & 15);
                bv[fc] = *reinterpret_cast<const short8*>(
                    Vt + ((size_t)b * D + d) * S + (size_t)kt * 64 + ks * 32 + (lane >> 4) * 8);
            }
            #pragma unroll
            for (int fr = 0; fr < 4; ++fr) {
                short8 a = *reinterpret_cast<const short8*>(&sP[fr * 16 + (lane & 15)][ks * 32 + (lane >> 4) * 8]);
                #pragma unroll
                for (int fc = 0; fc < 6; ++fc)
                    acc[fr][fc] = MFMA_BF16(a, bv[fc], acc[fr][fc], 0, 0, 0);
            }
        }
    }

    // ---- epilogue: O = acc / l ----
    #pragma unroll
    for (int fr = 0; fr < 4; ++fr) {
        #pragma unroll
        for (int r = 0; r < 4; ++r) {
            const int row = fr * 16 + (lane >> 4) * 4 + r;
            const float inv = 1.0f / l_run[row];
            const size_t obase = ((size_t)b * S + (size_t)qtile * 64 + row) * D;
            #pragma unroll
            for (int fc = 0; fc < 6; ++fc) {
                const int col = w * 96 + fc * 16 + (lane & 15);
                out[obase + col] = acc[fr][fc][r] * inv;
            }
        }
    }
}

extern "C" void kernel_launch(void* const* d_in, const int* in_sizes, int n_in,
                              void* d_out, int out_size, void* d_ws, size_t ws_size,
                              hipStream_t stream) {
    const float* x  = (const float*)d_in[0];
    const float* Wq = (const float*)d_in[1];
    const float* Wk = (const float*)d_in[2];
    const float* Wv = (const float*)d_in[3];
    float* out = (float*)d_out;

    unsigned short* q  = (unsigned short*)d_ws;                 // [16384,768] bf16
    unsigned short* k  = q + (size_t)16384 * 768;               // [16384,768] bf16
    unsigned short* vt = k + (size_t)16384 * 768;               // [4,768,4096] bf16
    (void)in_sizes; (void)n_in; (void)out_size; (void)ws_size;

    qkv_gemm<<<dim3(128, 6, 3), 256, 0, stream>>>(x, Wq, Wk, Wv, q, k, vt);
    attn_fwd<<<dim3(64, 4), 512, 0, stream>>>(q, k, vt, out);
}